// Round 2
// baseline (948.926 us; speedup 1.0000x reference)
//
#include <hip/hip_runtime.h>
#include <stdint.h>
#include <stddef.h>

// C[4096,11008] = X[4096,4096] @ W^T,  W = (sext4(nib) - zero)*scale, group=128.
// R2: (1) XCD-stripe block swizzle (bid%8 -> fixed m-tile, sweep n) so the 1MB
//     A tile stays hot in each XCD's 4MB L2  (R1 was fetch-bound: 1.6GB FETCH).
// (2) W stays 4-bit into the GEMM: prepass repacks int32-per-byte -> true packed
//     nibbles (90MB -> 21.5MB, ^0x88 so signed dequant becomes affine).
// (3) In-register dequant via f16 trick: f16(0x5800|(q<<3)) = 128+q, then
//     one v_pk_fma_f16: w = s*val - s*(136+z).  v_perm_b32 builds the halves.
// (4) A,B share a within-8 K permutation [0,2,4,6,1,3,5,7] (dot invariant);
//     X->f16 prepass applies it so A can use global_load_lds width=16.

#define M_TOK 4096
#define K_IN  4096
#define N_OUT 11008
#define QGROUPS 32
#define NBLK (N_OUT / 128)          // 86
#define MBLK (M_TOK / 128)          // 32
#define SUPER (8 * NBLK)            // 688

typedef _Float16 h8v __attribute__((ext_vector_type(8)));
typedef float    f4v __attribute__((ext_vector_type(4)));

__device__ __forceinline__ void gload16(const void* g, void* l) {
  __builtin_amdgcn_global_load_lds(
      (__attribute__((address_space(1))) void*)(g),
      (__attribute__((address_space(3))) void*)(l),
      16, 0, 0);
}

// ---- prepass 1: X f32 -> f16, with within-8 perm [0,2,4,6,1,3,5,7] ----
__global__ __launch_bounds__(256) void cvt_x_kernel(const float* __restrict__ x,
                                                    _Float16* __restrict__ xh) {
  size_t t = (size_t)blockIdx.x * 256 + threadIdx.x;
  const float4* s = (const float4*)x + t * 2;
  float4 a = s[0], b = s[1];          // a: k0..3, b: k4..7
  h8v o;
  o[0] = (_Float16)a.x; o[1] = (_Float16)a.z; o[2] = (_Float16)b.x; o[3] = (_Float16)b.z;
  o[4] = (_Float16)a.y; o[5] = (_Float16)a.w; o[6] = (_Float16)b.y; o[7] = (_Float16)b.w;
  ((h8v*)xh)[t] = o;
}

// ---- prepass 2: int32-per-byte -> packed nibble bytes, XOR 0x88 ----
__global__ __launch_bounds__(256) void repack_w_kernel(const int* __restrict__ wp,
                                                       uint32_t* __restrict__ wq) {
  size_t t = (size_t)blockIdx.x * 256 + threadIdx.x;   // 16 in-int32 -> 16 out bytes
  const int4* src = (const int4*)wp + t * 4;
  uint32_t d[4];
#pragma unroll
  for (int j = 0; j < 4; ++j) {
    int4 v = src[j];
    d[j] = (((uint32_t)v.x & 255u) | (((uint32_t)v.y & 255u) << 8) |
            (((uint32_t)v.z & 255u) << 16) | (((uint32_t)v.w & 255u) << 24)) ^ 0x88888888u;
  }
  uint4 o; o.x = d[0]; o.y = d[1]; o.z = d[2]; o.w = d[3];
  ((uint4*)wq)[t] = o;
}

// ---- GEMM: 128x128x64 tile, 4 waves, mfma_f32_16x16x32_f16 ----
// LDS unit(row,kb) at index row*8 + (kb ^ (row&7)); unit = 16B = 8 f16 (k-perm'd).
__global__ __launch_bounds__(256, 2) void gemm_kernel(
    const _Float16* __restrict__ Ah,     // f16 X [M][K] (perm'd within 8)
    const uint32_t* __restrict__ Wq,     // packed nibbles [N][K/8 dwords], ^0x88
    const float* __restrict__ WS,
    const int* __restrict__ WZ,
    float* __restrict__ C) {
  __shared__ __align__(16) short As[128 * 64];
  __shared__ __align__(16) short Bs[128 * 64];

  const int tid = threadIdx.x;
  const int lane = tid & 63;
  const int wid = tid >> 6;
  // XCD-stripe swizzle: 688 = 8*86; bid%8 = XCD (round-robin heuristic).
  int bid = blockIdx.x;
  int sup = bid / SUPER;
  int rem = bid - sup * SUPER;
  const int m0 = (sup * 8 + (rem & 7)) * 128;
  const int n0 = (rem >> 3) * 128;

  const int wm = (wid >> 1) * 64;
  const int wn = (wid & 1) * 64;
  const int quad = lane >> 4;
  const int lrow = lane & 15;
  const int sw = lrow & 7;
  const int srl = lane >> 3;            // A staging: row in slab
  const int skb = (lane & 7) ^ srl;     // A staging: swizzled k-unit
  const int brow = tid >> 1;            // B staging: row 0..127
  const int bhalf = tid & 1;            // B staging: k-half (32 elems)

  f4v acc[4][4];
#pragma unroll
  for (int i = 0; i < 4; ++i)
#pragma unroll
    for (int j = 0; j < 4; ++j) acc[i][j] = (f4v){0.f, 0.f, 0.f, 0.f};

  const uint32_t* wrow = Wq + (size_t)(n0 + brow) * (K_IN / 8) + bhalf * 4;
  const int sbase = (n0 + brow) * QGROUPS;

  // prefetch kt=0
  uint4 pw = *(const uint4*)wrow;
  float s = WS[sbase];
  float zf = (float)WZ[sbase];

  for (int kt = 0; kt < K_IN / 64; ++kt) {
    const int k0 = kt * 64;
    __syncthreads();
    // A staging: async global->LDS, 16B/lane, wave-uniform base
#pragma unroll
    for (int j = 0; j < 4; ++j) {
      int slab = wid * 4 + j;
      int row = slab * 8 + srl;
      gload16(Ah + (size_t)(m0 + row) * K_IN + k0 + skb * 8,
              (char*)As + slab * 1024);
    }
    // B staging: dequant 32 weights from registers
    {
      _Float16 sh = (_Float16)s;
      _Float16 ch = (_Float16)(-s * (136.0f + zf));
      h8v sv8, cv8;
#pragma unroll
      for (int i = 0; i < 8; ++i) { sv8[i] = sh; cv8[i] = ch; }
      uint32_t wv[4] = {pw.x, pw.y, pw.z, pw.w};
#pragma unroll
      for (int j = 0; j < 4; ++j) {
        uint32_t w = wv[j];
        uint32_t ea = (w & 0x0F0F0F0Fu) << 3;   // even elems, q<<3 per byte
        uint32_t eb = (w >> 1) & 0x78787878u;   // odd  elems, q<<3 per byte
        union { uint32_t d[4]; h8v v; } u;
        u.d[0] = __builtin_amdgcn_perm(0x58585858u, ea, 0x04010400u); // (q0,q2)
        u.d[1] = __builtin_amdgcn_perm(0x58585858u, ea, 0x04030402u); // (q4,q6)
        u.d[2] = __builtin_amdgcn_perm(0x58585858u, eb, 0x04010400u); // (q1,q3)
        u.d[3] = __builtin_amdgcn_perm(0x58585858u, eb, 0x04030402u); // (q5,q7)
        u.v = __builtin_elementwise_fma(u.v, sv8, cv8);               // 4x v_pk_fma_f16
        int kb = bhalf * 4 + j;
        int unit = brow * 8 + (kb ^ (brow & 7));
        *(h8v*)((char*)Bs + unit * 16) = u.v;   // ds_write_b128, conflict-free
      }
    }
    __syncthreads();
    // prefetch next iter's packed word + scales; latency hides under MFMA
    if (kt < K_IN / 64 - 1) {
      pw = *(const uint4*)(wrow + (kt + 1) * 8);
      int g2 = (k0 + 64) >> 7;
      s = WS[sbase + g2];
      zf = (float)WZ[sbase + g2];
    }
    // MFMA phase
#pragma unroll
    for (int ks = 0; ks < 2; ++ks) {
      h8v af[4], bf[4];
#pragma unroll
      for (int mi = 0; mi < 4; ++mi) {
        int unit = (wm + mi * 16 + lrow) * 8 + ((ks * 4 + quad) ^ sw);
        af[mi] = *(const h8v*)((char*)As + unit * 16);
      }
#pragma unroll
      for (int ni = 0; ni < 4; ++ni) {
        int unit = (wn + ni * 16 + lrow) * 8 + ((ks * 4 + quad) ^ sw);
        bf[ni] = *(const h8v*)((char*)Bs + unit * 16);
      }
#pragma unroll
      for (int mi = 0; mi < 4; ++mi)
#pragma unroll
        for (int ni = 0; ni < 4; ++ni)
          acc[mi][ni] = __builtin_amdgcn_mfma_f32_16x16x32_f16(
              af[mi], bf[ni], acc[mi][ni], 0, 0, 0);
    }
  }

  // epilogue: C/D layout col=lane&15 (n), row=quad*4+reg (m)
#pragma unroll
  for (int mi = 0; mi < 4; ++mi) {
#pragma unroll
    for (int r = 0; r < 4; ++r) {
      int m = m0 + wm + mi * 16 + quad * 4 + r;
      float* crow = C + (size_t)m * N_OUT + n0 + wn + lrow;
#pragma unroll
      for (int ni = 0; ni < 4; ++ni) crow[ni * 16] = acc[mi][ni][r];
    }
  }
}

extern "C" void kernel_launch(void* const* d_in, const int* in_sizes, int n_in,
                              void* d_out, int out_size, void* d_ws, size_t ws_size,
                              hipStream_t stream) {
  const float* x   = (const float*)d_in[0];
  const int*   wp  = (const int*)d_in[1];
  const float* wsc = (const float*)d_in[2];
  const int*   wz  = (const int*)d_in[3];
  float* out = (float*)d_out;

  _Float16* Ah = (_Float16*)d_ws;                                   // 32 MiB
  uint32_t* Wq = (uint32_t*)((char*)d_ws + (size_t)M_TOK * K_IN * 2); // 21.5 MiB

  cvt_x_kernel<<<(M_TOK * (size_t)K_IN) / (8 * 256), 256, 0, stream>>>(x, Ah);
  repack_w_kernel<<<((size_t)N_OUT * K_IN / 2) / (16 * 256), 256, 0, stream>>>(wp, Wq);
  gemm_kernel<<<MBLK * NBLK, 256, 0, stream>>>(Ah, Wq, wsc, wz, out);
}

// Round 3
// 718.117 us; speedup vs baseline: 1.3214x; 1.3214x over previous
//
#include <hip/hip_runtime.h>
#include <stdint.h>
#include <stddef.h>

// C[4096,11008] = X[4096,4096] @ W^T,  W = (sext4(nib) - zero)*scale, group=128.
// R3: (1) XCD affinity via s_getreg(HW_REG_XCC_ID) + per-XCD atomic tile queues
//     (R2's bid%8 swizzle assumed an unverified dispatch mapping and destroyed
//      A-reuse; this is dispatch-agnostic and correct by pigeonhole).
// (2) Packed-B retiled by prepass into per-(ntile,kt) 4KB chunks, lane i owns
//     bytes [16i,16i+16) -> one coalesced dwordx4 per thread per kt, prefetched
//     one kt ahead (R2's 32B-per-2KB-row reads quarter-used cache lines).
// (3) GEMM core unchanged: 128x128x64, mfma_f32_16x16x32_f16, f16-trick dequant
//     (f16(0x5800|(q<<3)) = 128+q), XOR-swizzled LDS units.

#define M_TOK 4096
#define K_IN  4096
#define N_OUT 11008
#define QGROUPS 32
#define MT 32
#define NT 86
#define TILES (MT * NT)       // 2752
#define PER_XCD (TILES / 8)   // 344

#define BT_OFF   ((size_t)M_TOK * K_IN * 2)          // Ah: 32 MiB
#define CTR_OFF  (BT_OFF + 23068672)                 // Bt: 22544384 B, padded

typedef _Float16 h8v __attribute__((ext_vector_type(8)));
typedef float    f4v __attribute__((ext_vector_type(4)));

__device__ __forceinline__ void gload16(const void* g, void* l) {
  __builtin_amdgcn_global_load_lds(
      (__attribute__((address_space(1))) void*)(g),
      (__attribute__((address_space(3))) void*)(l),
      16, 0, 0);
}

// ---- prepass 1: X f32 -> f16, within-8 perm [0,2,4,6,1,3,5,7] ----
__global__ __launch_bounds__(256) void cvt_x_kernel(const float* __restrict__ x,
                                                    _Float16* __restrict__ xh) {
  size_t t = (size_t)blockIdx.x * 256 + threadIdx.x;
  const float4* s = (const float4*)x + t * 2;
  float4 a = s[0], b = s[1];
  h8v o;
  o[0] = (_Float16)a.x; o[1] = (_Float16)a.z; o[2] = (_Float16)b.x; o[3] = (_Float16)b.z;
  o[4] = (_Float16)a.y; o[5] = (_Float16)a.w; o[6] = (_Float16)b.y; o[7] = (_Float16)b.w;
  ((h8v*)xh)[t] = o;
}

// ---- prepass 2: int32-per-byte -> tiled packed nibbles, ^0x88 ----
// Bt chunk layout: offset(t,kt,tid) = ((t*64+kt)*256+tid)*16 bytes; the 16 bytes
// are exactly what gemm thread `tid` dequants for n-tile t, k-step kt.
__global__ __launch_bounds__(256) void repack_w_kernel(const int* __restrict__ wp,
                                                       uint32_t* __restrict__ bt) {
  size_t tg = (size_t)blockIdx.x * 256 + threadIdx.x;
  int tid = (int)(tg & 255);
  int kt  = (int)((tg >> 8) & 63);
  int t   = (int)(tg >> 14);
  int row = t * 128 + (tid >> 1);
  const int4* src = (const int4*)(wp + (size_t)row * 2048 + kt * 32 + (tid & 1) * 16);
  uint32_t d[4];
#pragma unroll
  for (int j = 0; j < 4; ++j) {
    int4 v = src[j];
    d[j] = (((uint32_t)v.x & 255u) | (((uint32_t)v.y & 255u) << 8) |
            (((uint32_t)v.z & 255u) << 16) | (((uint32_t)v.w & 255u) << 24)) ^ 0x88888888u;
  }
  uint4 o; o.x = d[0]; o.y = d[1]; o.z = d[2]; o.w = d[3];
  ((uint4*)bt)[tg] = o;
}

// ---- GEMM ----
__global__ __launch_bounds__(256, 2) void gemm_kernel(
    const _Float16* __restrict__ Ah,
    const uint32_t* __restrict__ Bt,
    const float* __restrict__ WS,
    const int* __restrict__ WZ,
    unsigned int* __restrict__ ctr,
    float* __restrict__ C) {
  __shared__ __align__(16) short As[128 * 64];
  __shared__ __align__(16) short Bs[128 * 64];
  __shared__ int tileId;

  const int tid = threadIdx.x;
  // --- dispatch-agnostic XCD-affine tile assignment ---
  if (tid == 0) {
    int xcd = __builtin_amdgcn_s_getreg(63508) & 7;  // hwreg(HW_REG_XCC_ID=20, 0, 32)
    int got = -1;
#pragma unroll 1
    for (int off = 0; off < 8; ++off) {
      int x = (xcd + off) & 7;
      unsigned idx = atomicAdd(&ctr[x], 1u);
      if (idx < PER_XCD) { got = x * PER_XCD + (int)idx; break; }
    }
    tileId = got;  // pigeonhole: grid size == TILES, so got >= 0 always
  }
  __syncthreads();
  const int tl = tileId;
  const int x  = tl / PER_XCD;
  const int e  = tl - x * PER_XCD;
  const int r  = e / NT;
  const int nt = e - r * NT;
  const int m0 = (x + 8 * r) * 128;   // rows {x, x+8, x+16, x+24}: A-row L2-resident per XCD
  const int n0 = nt * 128;

  const int lane = tid & 63;
  const int wid  = tid >> 6;
  const int wm = (wid >> 1) * 64;
  const int wn = (wid & 1) * 64;
  const int quad = lane >> 4;
  const int lrow = lane & 15;
  const int sw = lrow & 7;
  const int srl = lane >> 3;
  const int skb = (lane & 7) ^ srl;
  const int brow = tid >> 1;
  const int bhalf = tid & 1;

  f4v acc[4][4];
#pragma unroll
  for (int i = 0; i < 4; ++i)
#pragma unroll
    for (int j = 0; j < 4; ++j) acc[i][j] = (f4v){0.f, 0.f, 0.f, 0.f};

  const uint4* bsrc = (const uint4*)Bt + (size_t)nt * 64 * 256 + tid;
  const int sbase = (n0 + brow) * QGROUPS;

  uint4 pw = bsrc[0];
  for (int kt = 0; kt < 64; ++kt) {
    // prefetch next packed word early; in flight across the barrier drain
    int ktn = (kt < 63) ? kt + 1 : 63;
    uint4 pn = bsrc[(size_t)ktn * 256];
    int g = kt >> 1;
    float s  = WS[sbase + g];
    float zf = (float)WZ[sbase + g];

    __syncthreads();
    // A staging: async global->LDS, swizzled source addressing
#pragma unroll
    for (int j = 0; j < 4; ++j) {
      int slab = wid * 4 + j;
      int row = slab * 8 + srl;
      gload16(Ah + (size_t)(m0 + row) * K_IN + kt * 64 + skb * 8,
              (char*)As + slab * 1024);
    }
    // B staging: dequant 32 weights from registers
    {
      _Float16 sh = (_Float16)s;
      _Float16 ch = (_Float16)(-s * (136.0f + zf));
      h8v sv8, cv8;
#pragma unroll
      for (int i = 0; i < 8; ++i) { sv8[i] = sh; cv8[i] = ch; }
      uint32_t wv[4] = {pw.x, pw.y, pw.z, pw.w};
#pragma unroll
      for (int j = 0; j < 4; ++j) {
        uint32_t w = wv[j];
        uint32_t ea = (w & 0x0F0F0F0Fu) << 3;
        uint32_t eb = (w >> 1) & 0x78787878u;
        union { uint32_t d[4]; h8v v; } u;
        u.d[0] = __builtin_amdgcn_perm(0x58585858u, ea, 0x04010400u);
        u.d[1] = __builtin_amdgcn_perm(0x58585858u, ea, 0x04030402u);
        u.d[2] = __builtin_amdgcn_perm(0x58585858u, eb, 0x04010400u);
        u.d[3] = __builtin_amdgcn_perm(0x58585858u, eb, 0x04030402u);
        u.v = __builtin_elementwise_fma(u.v, sv8, cv8);
        int kb = bhalf * 4 + j;
        int unit = brow * 8 + (kb ^ (brow & 7));
        *(h8v*)((char*)Bs + unit * 16) = u.v;
      }
    }
    __syncthreads();

#pragma unroll
    for (int ks = 0; ks < 2; ++ks) {
      h8v af[4], bf[4];
#pragma unroll
      for (int mi = 0; mi < 4; ++mi) {
        int unit = (wm + mi * 16 + lrow) * 8 + ((ks * 4 + quad) ^ sw);
        af[mi] = *(const h8v*)((char*)As + unit * 16);
      }
#pragma unroll
      for (int ni = 0; ni < 4; ++ni) {
        int unit = (wn + ni * 16 + lrow) * 8 + ((ks * 4 + quad) ^ sw);
        bf[ni] = *(const h8v*)((char*)Bs + unit * 16);
      }
#pragma unroll
      for (int mi = 0; mi < 4; ++mi)
#pragma unroll
        for (int ni = 0; ni < 4; ++ni)
          acc[mi][ni] = __builtin_amdgcn_mfma_f32_16x16x32_f16(
              af[mi], bf[ni], acc[mi][ni], 0, 0, 0);
    }
    pw = pn;
  }

  // epilogue: C/D layout col=lane&15 (n), row=quad*4+reg (m)
#pragma unroll
  for (int mi = 0; mi < 4; ++mi) {
#pragma unroll
    for (int rr = 0; rr < 4; ++rr) {
      int m = m0 + wm + mi * 16 + quad * 4 + rr;
      float* crow = C + (size_t)m * N_OUT + n0 + wn + lrow;
#pragma unroll
      for (int ni = 0; ni < 4; ++ni) crow[ni * 16] = acc[mi][ni][rr];
    }
  }
}

extern "C" void kernel_launch(void* const* d_in, const int* in_sizes, int n_in,
                              void* d_out, int out_size, void* d_ws, size_t ws_size,
                              hipStream_t stream) {
  const float* x   = (const float*)d_in[0];
  const int*   wp  = (const int*)d_in[1];
  const float* wsc = (const float*)d_in[2];
  const int*   wz  = (const int*)d_in[3];
  float* out = (float*)d_out;

  _Float16* Ah = (_Float16*)d_ws;
  uint32_t* Bt = (uint32_t*)((char*)d_ws + BT_OFF);
  unsigned int* ctr = (unsigned int*)((char*)d_ws + CTR_OFF);

  hipMemsetAsync(ctr, 0, 8 * sizeof(unsigned int), stream);
  cvt_x_kernel<<<(M_TOK * (size_t)K_IN) / (8 * 256), 256, 0, stream>>>(x, Ah);
  repack_w_kernel<<<(size_t)NT * 64, 256, 0, stream>>>(wp, Bt);
  gemm_kernel<<<TILES, 256, 0, stream>>>(Ah, Bt, wsc, wz, ctr, out);
}